// Round 1
// baseline (442.596 us; speedup 1.0000x reference)
//
#include <hip/hip_runtime.h>
#include <hip/hip_bf16.h>
#include <math.h>

// Problem constants
#define BDIM 32
#define CDIM 256
#define HW   1024          // 32*32
#define NVEC 32768         // B*H*W
#define NE   1024
#define ZSIZE 8388608      // 32*256*32*32

// Output layout (floats): [loss(1)][z_q(ZSIZE)][perp(1)][idx(NVEC)][z_q1(ZSIZE)]
#define OUT_LOSS 0
#define OUT_ZQ   1
#define OUT_PERP 8388609
#define OUT_IDX  8388610
#define OUT_ZQ1  8421378

// Workspace layout (bytes): [0:8 double loss][64:4160 int hist][4224:8320 float enorm][8448: int idx]
#define WS_HIST  64
#define WS_ENORM 4224
#define WS_IDX   8448

// ---------------- codebook norms: ||e_j||^2 ----------------
__global__ __launch_bounds__(256) void vq_enorm(const float* __restrict__ emb,
                                                float* __restrict__ enorm) {
    int code = blockIdx.x * 4 + (threadIdx.x >> 6);
    int lane = threadIdx.x & 63;
    float4 v = *(const float4*)(emb + (size_t)code * CDIM + lane * 4);
    float s = v.x * v.x + v.y * v.y + v.z * v.z + v.w * v.w;
    for (int off = 32; off; off >>= 1) s += __shfl_down(s, off, 64);
    if (lane == 0) enorm[code] = s;
}

// ---------------- fused distance-GEMM + argmax ----------------
// score(n,j) = z_n . e_j - 0.5*||e_j||^2  (argmax == argmin of distance)
// BM=64 rows/block, BN=128 code chunk, BK=64, micro-tile 4x8.
__global__ __launch_bounds__(256) void vq_argmin(
    const float* __restrict__ z, const float* __restrict__ emb,
    const float* __restrict__ enorm, int* __restrict__ idx_ws,
    float* __restrict__ idx_out, int* __restrict__ hist)
{
    __shared__ float zs[64 * 64];    // [k][n], stride 64
    __shared__ float es[64 * 132];   // [k][j], stride 132 (pad 4: 16B-aligned rows)

    const int tid = threadIdx.x;
    const int tn  = tid & 15;        // row group: rows tn*4 .. tn*4+3
    const int tj  = tid >> 4;        // col group: cols tj*8 .. tj*8+7
    const int n0  = blockIdx.x * 64;
    const int b_img = n0 >> 10;
    const int hw0   = n0 & 1023;
    const float* zb = z + (size_t)b_img * (CDIM * HW) + hw0;

    float best[4];
    int   bi[4];
#pragma unroll
    for (int a = 0; a < 4; ++a) { best[a] = -3.0e38f; bi[a] = 0; }

    for (int j0 = 0; j0 < NE; j0 += 128) {
        float acc[4][8];
#pragma unroll
        for (int a = 0; a < 4; ++a)
#pragma unroll
            for (int b = 0; b < 8; ++b) acc[a][b] = 0.f;

        for (int k0 = 0; k0 < CDIM; k0 += 64) {
            // stage z tile: global already [channel][n]-major for this block -> no transpose
#pragma unroll
            for (int r = 0; r < 4; ++r) {
                int u = r * 256 + tid;
                int row = u >> 4;           // 0..63 (channel within chunk)
                int col = (u & 15) * 4;     // 0..60
                float4 v = *(const float4*)(zb + (size_t)(k0 + row) * HW + col);
                *(float4*)(zs + row * 64 + col) = v;
            }
            // stage e tile, transposed ([j][c] -> [c][j])
#pragma unroll
            for (int r = 0; r < 8; ++r) {
                int u = r * 256 + tid;
                int j  = u >> 4;            // 0..127
                int cq = (u & 15) * 4;      // 0..60
                float4 v = *(const float4*)(emb + (size_t)(j0 + j) * CDIM + k0 + cq);
                es[(cq + 0) * 132 + j] = v.x;
                es[(cq + 1) * 132 + j] = v.y;
                es[(cq + 2) * 132 + j] = v.z;
                es[(cq + 3) * 132 + j] = v.w;
            }
            __syncthreads();
#pragma unroll 8
            for (int k = 0; k < 64; ++k) {
                float4 zv = *(const float4*)(zs + k * 64 + tn * 4);
                float4 e0 = *(const float4*)(es + k * 132 + tj * 8);
                float4 e1 = *(const float4*)(es + k * 132 + tj * 8 + 4);
                float zr[4] = { zv.x, zv.y, zv.z, zv.w };
                float er[8] = { e0.x, e0.y, e0.z, e0.w, e1.x, e1.y, e1.z, e1.w };
#pragma unroll
                for (int a = 0; a < 4; ++a)
#pragma unroll
                    for (int b = 0; b < 8; ++b)
                        acc[a][b] = fmaf(zr[a], er[b], acc[a][b]);
            }
            __syncthreads();
        }
        // fold -0.5*||e||^2 and update running argmax (j ascending -> strict > keeps first)
#pragma unroll
        for (int b = 0; b < 8; ++b) {
            int j = j0 + tj * 8 + b;
            float hn = 0.5f * enorm[j];
#pragma unroll
            for (int a = 0; a < 4; ++a) {
                float s = acc[a][b] - hn;
                if (s > best[a]) { best[a] = s; bi[a] = j; }
            }
        }
    }

    // cross-thread (over tj groups) argmax reduction; reuse tiles as scratch
    float* sred = zs;            // 1024 floats
    int*   ired = (int*)es;      // 1024 ints
#pragma unroll
    for (int a = 0; a < 4; ++a) { sred[tid * 4 + a] = best[a]; ired[tid * 4 + a] = bi[a]; }
    __syncthreads();
    if (tid < 64) {
        int tn_own = tid >> 2;
        int mi = tid & 3;
        float bs = -3.4e38f; int bj = 0;
        for (int t2 = 0; t2 < 16; ++t2) {
            int src = (t2 * 16 + tn_own) * 4 + mi;
            float s = sred[src];
            int j = ired[src];
            if (s > bs || (s == bs && j < bj)) { bs = s; bj = j; }
        }
        int n = n0 + tid;
        idx_ws[n]  = bj;
        idx_out[n] = (float)bj;
        atomicAdd(&hist[bj], 1);
    }
}

// ---------------- gather + outputs + loss partial sums ----------------
__global__ __launch_bounds__(256) void vq_gather(
    const float* __restrict__ z, const float* __restrict__ emb,
    const int* __restrict__ idx_ws, float* __restrict__ zq,
    float* __restrict__ zq1, double* __restrict__ loss_sum)
{
    int tid = threadIdx.x;
    size_t i0 = ((size_t)blockIdx.x * 256 + tid) * 4;
    int hw = (int)(i0 & 1023);
    int c  = (int)((i0 >> 10) & 255);
    int b  = (int)(i0 >> 18);
    int nb = (b << 10) + hw;

    float4 zv = *(const float4*)(z + i0);
    float zr[4] = { zv.x, zv.y, zv.z, zv.w };
    float q1v[4], qv[4];
    float ls = 0.f;
#pragma unroll
    for (int k = 0; k < 4; ++k) {
        int id = idx_ws[nb + k];
        float e = emb[(size_t)id * CDIM + c];
        float d = e - zr[k];
        q1v[k] = e;
        qv[k]  = zr[k] + d;       // match ref: zp + (z_q1 - zp)
        ls += d * d;
    }
    // outputs are float-offset by 1 / 8421378 -> not 16B aligned: scalar stores
#pragma unroll
    for (int k = 0; k < 4; ++k) { zq[i0 + k] = qv[k]; zq1[i0 + k] = q1v[k]; }

    for (int off = 32; off; off >>= 1) ls += __shfl_down(ls, off, 64);
    __shared__ float wred[4];
    int lane = tid & 63, wv = tid >> 6;
    if (lane == 0) wred[wv] = ls;
    __syncthreads();
    if (tid == 0) {
        float t = wred[0] + wred[1] + wred[2] + wred[3];
        atomicAdd(loss_sum, (double)t);
    }
}

// ---------------- finalize: loss scalar + perplexity ----------------
__global__ __launch_bounds__(1024) void vq_final(
    const int* __restrict__ hist, const double* __restrict__ loss_sum,
    float* __restrict__ out_loss, float* __restrict__ out_perp)
{
    int tid = threadIdx.x;
    float em = (float)hist[tid] * (1.0f / 32768.0f);
    float term = em * logf(em + 1e-10f);
    for (int off = 32; off; off >>= 1) term += __shfl_down(term, off, 64);
    __shared__ float red[16];
    int lane = tid & 63, wv = tid >> 6;
    if (lane == 0) red[wv] = term;
    __syncthreads();
    if (tid == 0) {
        float s = 0.f;
        for (int i = 0; i < 16; ++i) s += red[i];
        *out_perp = expf(-s);
        *out_loss = (float)(*loss_sum * 1.25 / 8388608.0);
    }
}

extern "C" void kernel_launch(void* const* d_in, const int* in_sizes, int n_in,
                              void* d_out, int out_size, void* d_ws, size_t ws_size,
                              hipStream_t stream) {
    const float* z   = (const float*)d_in[0];
    const float* emb = (const float*)d_in[1];
    float* out = (float*)d_out;
    char*  ws  = (char*)d_ws;

    double* loss_sum = (double*)ws;
    int*    hist     = (int*)(ws + WS_HIST);
    float*  enorm    = (float*)(ws + WS_ENORM);
    int*    idx_ws   = (int*)(ws + WS_IDX);

    // zero loss accumulator + histogram (ws is poisoned 0xAA before every call)
    hipMemsetAsync(d_ws, 0, 4224, stream);

    vq_enorm <<<256, 256, 0, stream>>>(emb, enorm);
    vq_argmin<<<512, 256, 0, stream>>>(z, emb, enorm, idx_ws, out + OUT_IDX, hist);
    vq_gather<<<8192, 256, 0, stream>>>(z, emb, idx_ws, out + OUT_ZQ, out + OUT_ZQ1, loss_sum);
    vq_final <<<1, 1024, 0, stream>>>(hist, loss_sum, out + OUT_LOSS, out + OUT_PERP);
}